// Round 1
// baseline (882.260 us; speedup 1.0000x reference)
//
#include <hip/hip_runtime.h>
#include <hip/hip_bf16.h>

__device__ __forceinline__ float elu_f(float x) {
    return x > 0.0f ? x : expm1f(x);
}

// ---------------- CSR build ----------------
__global__ void hist_kernel(const int* __restrict__ ei, int* __restrict__ deg, int E, int n) {
    int total = E + n;
    for (int i = blockIdx.x * blockDim.x + threadIdx.x; i < total; i += gridDim.x * blockDim.x) {
        int d = (i < E) ? ei[E + i] : (i - E);
        atomicAdd(&deg[d], 1);
    }
}

__global__ __launch_bounds__(1024) void scan_kernel(const int* __restrict__ deg, int* __restrict__ rowptr,
                                                    int* __restrict__ cursor, int n) {
    __shared__ int part[1024];
    int t = threadIdx.x;
    int CH = (n + 1023) >> 10;
    int base = t * CH;
    int sum = 0;
    for (int j = 0; j < CH; ++j) {
        int idx = base + j;
        if (idx < n) sum += deg[idx];
    }
    part[t] = sum;
    __syncthreads();
    for (int off = 1; off < 1024; off <<= 1) {
        int v = (t >= off) ? part[t - off] : 0;
        __syncthreads();
        part[t] += v;
        __syncthreads();
    }
    int ex = (t == 0) ? 0 : part[t - 1];
    for (int j = 0; j < CH; ++j) {
        int idx = base + j;
        if (idx < n) {
            rowptr[idx] = ex;
            cursor[idx] = ex;
            ex += deg[idx];
        }
    }
    if (t == 1023) rowptr[n] = part[1023];
}

__global__ void scatter_kernel(const int* __restrict__ ei, int* __restrict__ cursor,
                               int* __restrict__ csr_src, int E, int n) {
    int total = E + n;
    for (int i = blockIdx.x * blockDim.x + threadIdx.x; i < total; i += gridDim.x * blockDim.x) {
        int s, d;
        if (i < E) { s = ei[i]; d = ei[E + i]; }
        else       { s = i - E; d = s; }
        int pos = atomicAdd(&cursor[d], 1);
        csr_src[pos] = s;
    }
}

// ---------------- fp32 tiled GEMM: C[M x N] = A[M x 256] @ W[256 x N] (+bias) ----------------
template<int N>
__global__ __launch_bounds__(256) void gemm_kernel(const float* __restrict__ A, const float* __restrict__ W,
                                                   const float* __restrict__ bias, float* __restrict__ C,
                                                   int M) {
    const int K = 256;
    __shared__ float As[16][68];  // pad 64->68 (16B-aligned rows, conflict-light)
    __shared__ float Bs[16][64];
    int tid = threadIdx.x;
    int tx = tid & 15;    // n-group (4 cols each)
    int ty = tid >> 4;    // m-group (4 rows each)
    int row0 = blockIdx.x * 64;
    int col0 = blockIdx.y * 64;
    float acc[4][4] = {};
    for (int kt = 0; kt < K; kt += 16) {
        int ka = tid & 15;
        #pragma unroll
        for (int i = 0; i < 4; ++i) {
            int m = (tid >> 4) + 16 * i;
            int r = row0 + m;
            As[ka][m] = (r < M) ? A[(size_t)r * K + kt + ka] : 0.0f;
        }
        int nb = tid & 63;
        #pragma unroll
        for (int i = 0; i < 4; ++i) {
            int kb = (tid >> 6) + 4 * i;
            Bs[kb][nb] = W[(size_t)(kt + kb) * N + col0 + nb];
        }
        __syncthreads();
        #pragma unroll
        for (int k = 0; k < 16; ++k) {
            float4 av = *(const float4*)&As[k][ty * 4];
            float4 bv = *(const float4*)&Bs[k][tx * 4];
            float a[4] = {av.x, av.y, av.z, av.w};
            float b[4] = {bv.x, bv.y, bv.z, bv.w};
            #pragma unroll
            for (int i = 0; i < 4; ++i)
                #pragma unroll
                for (int j = 0; j < 4; ++j)
                    acc[i][j] += a[i] * b[j];
        }
        __syncthreads();
    }
    float4 bv = make_float4(0.f, 0.f, 0.f, 0.f);
    if (bias) bv = *(const float4*)&bias[col0 + tx * 4];
    #pragma unroll
    for (int i = 0; i < 4; ++i) {
        int r = row0 + ty * 4 + i;
        if (r < M) {
            float4 st;
            st.x = acc[i][0] + bv.x;
            st.y = acc[i][1] + bv.y;
            st.z = acc[i][2] + bv.z;
            st.w = acc[i][3] + bv.w;
            *(float4*)&C[(size_t)r * N + col0 + tx * 4] = st;
        }
    }
}

// ---------------- per-node attention halves: s[n,h], d[n,h] ----------------
template<int HEADS>
__global__ __launch_bounds__(256) void sd_kernel(const float* __restrict__ h, const float* __restrict__ a_src,
                                                 const float* __restrict__ a_dst, float* __restrict__ s_out,
                                                 float* __restrict__ d_out_, int nnodes) {
    int lane = threadIdx.x & 63;
    int node = blockIdx.x * 4 + (threadIdx.x >> 6);
    if (node >= nnodes) return;
    float4 hv = *(const float4*)&h[(size_t)node * 256 + lane * 4];
    float4 as = *(const float4*)&a_src[lane * 4];
    float4 ad = *(const float4*)&a_dst[lane * 4];
    float ps = hv.x * as.x + hv.y * as.y + hv.z * as.z + hv.w * as.w;
    float pd = hv.x * ad.x + hv.y * ad.y + hv.z * ad.z + hv.w * ad.w;
    const int GS = 64 / HEADS;  // lanes per head group
    #pragma unroll
    for (int off = 1; off < GS; off <<= 1) {
        ps += __shfl_xor(ps, off);
        pd += __shfl_xor(pd, off);
    }
    int g = lane / GS;
    int r = lane & (GS - 1);
    if (r == 0) s_out[(size_t)node * HEADS + g] = ps;
    if (r == 1) d_out_[(size_t)node * HEADS + g] = pd;
}

// ---------------- fused segment-softmax + aggregate + bias + ELU ----------------
// one wave per dst node; lane owns 4 contiguous output channels (cbase = lane*4)
template<int HEADS>
__global__ __launch_bounds__(256) void agg_kernel(const int* __restrict__ rowptr, const int* __restrict__ csr_src,
                                                  const float* __restrict__ h, const float* __restrict__ s_att,
                                                  const float* __restrict__ d_att, const float* __restrict__ bias,
                                                  float* __restrict__ out, int nnodes) {
    int lane = threadIdx.x & 63;
    int node = blockIdx.x * 4 + (threadIdx.x >> 6);
    if (node >= nnodes) return;
    int hh = (HEADS == 8) ? (lane >> 3) : 0;
    int cbase = lane * 4;  // == hh*CH + c0 for both configs
    int begin = rowptr[node], end = rowptr[node + 1];
    float dl = d_att[(size_t)node * HEADS + hh];
    // pass 1: per-head max over incoming edges
    float m = -1e30f;
    for (int i = begin; i < end; ++i) {
        int s = csr_src[i];
        float v = s_att[(size_t)s * HEADS + hh] + dl;
        v = (v < 0.0f) ? 0.2f * v : v;
        m = fmaxf(m, v);
    }
    // pass 2: denom + weighted row gather in one sweep
    float accx = 0.f, accy = 0.f, accz = 0.f, accw = 0.f, den = 0.f;
    for (int i = begin; i < end; ++i) {
        int s = csr_src[i];
        float v = s_att[(size_t)s * HEADS + hh] + dl;
        v = (v < 0.0f) ? 0.2f * v : v;
        float w = __expf(v - m);
        den += w;
        float4 hv = *(const float4*)&h[(size_t)s * 256 + cbase];
        accx += w * hv.x; accy += w * hv.y; accz += w * hv.z; accw += w * hv.w;
    }
    float inv = 1.0f / den;
    float4 bv = *(const float4*)&bias[cbase];
    float4 r;
    r.x = elu_f(accx * inv + bv.x);
    r.y = elu_f(accy * inv + bv.y);
    r.z = elu_f(accz * inv + bv.z);
    r.w = elu_f(accw * inv + bv.w);
    *(float4*)&out[(size_t)node * 256 + cbase] = r;
}

extern "C" void kernel_launch(void* const* d_in, const int* in_sizes, int n_in,
                              void* d_out, int out_size, void* d_ws, size_t ws_size,
                              hipStream_t stream) {
    const float* x      = (const float*)d_in[0];
    const int*   ei     = (const int*)d_in[1];
    const float* W1     = (const float*)d_in[2];
    const float* a_src1 = (const float*)d_in[3];
    const float* a_dst1 = (const float*)d_in[4];
    const float* b1     = (const float*)d_in[5];
    const float* W2     = (const float*)d_in[6];
    const float* a_src2 = (const float*)d_in[7];
    const float* a_dst2 = (const float*)d_in[8];
    const float* b2     = (const float*)d_in[9];
    const float* Wlin   = (const float*)d_in[10];
    const float* blin   = (const float*)d_in[11];
    float* out = (float*)d_out;

    const int N = in_sizes[0] / 256;   // 50000 nodes
    const int E = in_sizes[1] / 2;     // 800000 edges
    const int ET = E + N;              // + self loops

    char* p = (char*)d_ws;
    auto alloc = [&](size_t bytes) {
        void* r = (void*)p;
        p += (bytes + 255) & ~size_t(255);
        return r;
    };
    float* bufA   = (float*)alloc((size_t)N * 256 * 4);  // h1, then h2pre
    float* bufB   = (float*)alloc((size_t)N * 256 * 4);  // out1, then out2
    float* s1     = (float*)alloc((size_t)N * 8 * 4);
    float* d1     = (float*)alloc((size_t)N * 8 * 4);
    float* s2     = (float*)alloc((size_t)N * 4);
    float* d2     = (float*)alloc((size_t)N * 4);
    int*   deg    = (int*)alloc((size_t)N * 4);
    int*   cursor = (int*)alloc((size_t)N * 4);
    int*   rowptr = (int*)alloc((size_t)(N + 1) * 4);
    int*   csr    = (int*)alloc((size_t)ET * 4);

    // ---- CSR build ----
    hipMemsetAsync(deg, 0, (size_t)N * 4, stream);
    hist_kernel<<<(ET + 255) / 256, 256, 0, stream>>>(ei, deg, E, N);
    scan_kernel<<<1, 1024, 0, stream>>>(deg, rowptr, cursor, N);
    scatter_kernel<<<(ET + 255) / 256, 256, 0, stream>>>(ei, cursor, csr, E, N);

    // ---- layer 1 ----
    dim3 g1((N + 63) / 64, 4);
    gemm_kernel<256><<<g1, 256, 0, stream>>>(x, W1, nullptr, bufA, N);
    int nodeBlocks = (N + 3) / 4;
    sd_kernel<8><<<nodeBlocks, 256, 0, stream>>>(bufA, a_src1, a_dst1, s1, d1, N);
    agg_kernel<8><<<nodeBlocks, 256, 0, stream>>>(rowptr, csr, bufA, s1, d1, b1, bufB, N);

    // ---- layer 2 ----
    gemm_kernel<256><<<g1, 256, 0, stream>>>(bufB, W2, nullptr, bufA, N);
    sd_kernel<1><<<nodeBlocks, 256, 0, stream>>>(bufA, a_src2, a_dst2, s2, d2, N);
    agg_kernel<1><<<nodeBlocks, 256, 0, stream>>>(rowptr, csr, bufA, s2, d2, b2, bufB, N);

    // ---- final linear ----
    dim3 g2((N + 63) / 64, 1);
    gemm_kernel<64><<<g2, 256, 0, stream>>>(bufB, Wlin, blin, out, N);
}

// Round 2
// 717.554 us; speedup vs baseline: 1.2295x; 1.2295x over previous
//
#include <hip/hip_runtime.h>
#include <hip/hip_bf16.h>

typedef __attribute__((ext_vector_type(8))) short short8;
typedef __attribute__((ext_vector_type(4))) float f32x4;

#define GLL(g, s) __builtin_amdgcn_global_load_lds(                        \
    (const __attribute__((address_space(1))) void*)(g),                    \
    (__attribute__((address_space(3))) void*)(s), 16, 0, 0)

__device__ __forceinline__ ushort f2bf(float f) {
    unsigned u = __float_as_uint(f);
    u += 0x7fffu + ((u >> 16) & 1u);
    return (ushort)(u >> 16);
}
__device__ __forceinline__ float bf2f(ushort h) {
    return __uint_as_float(((unsigned)h) << 16);
}
__device__ __forceinline__ float elu_f(float x) {
    return x > 0.0f ? x : expm1f(x);
}
__device__ __forceinline__ float lrelu(float x) {
    return x < 0.0f ? 0.2f * x : x;
}

// ---------------- CSR build ----------------
__global__ void hist_kernel(const int* __restrict__ ei, int* __restrict__ deg, int E, int n) {
    int total = E + n;
    for (int i = blockIdx.x * blockDim.x + threadIdx.x; i < total; i += gridDim.x * blockDim.x) {
        int d = (i < E) ? ei[E + i] : (i - E);
        atomicAdd(&deg[d], 1);
    }
}

__global__ __launch_bounds__(1024) void scan_kernel(const int* __restrict__ deg, int* __restrict__ rowptr,
                                                    int* __restrict__ cursor, int n) {
    __shared__ int part[1024];
    int t = threadIdx.x;
    int CH = (n + 1023) >> 10;
    int base = t * CH;
    int sum = 0;
    for (int j = 0; j < CH; ++j) {
        int idx = base + j;
        if (idx < n) sum += deg[idx];
    }
    part[t] = sum;
    __syncthreads();
    for (int off = 1; off < 1024; off <<= 1) {
        int v = (t >= off) ? part[t - off] : 0;
        __syncthreads();
        part[t] += v;
        __syncthreads();
    }
    int ex = (t == 0) ? 0 : part[t - 1];
    for (int j = 0; j < CH; ++j) {
        int idx = base + j;
        if (idx < n) {
            rowptr[idx] = ex;
            cursor[idx] = ex;
            ex += deg[idx];
        }
    }
    if (t == 1023) rowptr[n] = part[1023];
}

__global__ void scatter_kernel(const int* __restrict__ ei, int* __restrict__ cursor,
                               int* __restrict__ csr_src, int E, int n) {
    int total = E + n;
    for (int i = blockIdx.x * blockDim.x + threadIdx.x; i < total; i += gridDim.x * blockDim.x) {
        int s, d;
        if (i < E) { s = ei[i]; d = ei[E + i]; }
        else       { s = i - E; d = s; }
        int pos = atomicAdd(&cursor[d], 1);
        csr_src[pos] = s;
    }
}

// ---------------- W pre-pack: W[K x N] fp32 -> fragment-major bf16 hi/lo ----------------
// layout: Wp[k/8][n][k%8] (so each K-step's 4-chunk block of the tile is one
// contiguous region and global_load_lds staging is linear & coalesced)
__global__ void wconv_kernel(const float* __restrict__ W, short* __restrict__ hi,
                             short* __restrict__ lo, int KN, int Ncols) {
    int idx = blockIdx.x * 256 + threadIdx.x;
    if (idx >= KN) return;
    int k = idx / Ncols, n = idx - k * Ncols;
    float v = W[idx];
    ushort h = f2bf(v);
    ushort l = f2bf(v - bf2f(h));
    size_t o = ((size_t)(k >> 3) * Ncols + n) * 8 + (k & 7);
    hi[o] = h;
    lo[o] = l;
}

// ---------------- split-bf16 MFMA GEMM: C[M x N] = A[M x 256] @ W[256 x N] (+bias) ----
// 64xN tile per block, BK=32, 4 waves, double-buffered LDS, 3-pass split:
// acc += Ahi@Bhi + Ahi@Blo + Alo@Bhi  (error ~2^-16 relative)
template<int N>
__global__ __launch_bounds__(256, 2) void gemm_mfma(const float* __restrict__ A,
                                                    const short* __restrict__ Bph,
                                                    const short* __restrict__ Bpl,
                                                    const float* __restrict__ bias,
                                                    float* __restrict__ C, int M) {
    constexpr int FN = (N == 256) ? 4 : 1;
    // fragment-major LDS: [kchunk][row/n][8 bf16] -> ds_read_b128 conflict-free
    __shared__ short Ah[2][2048], Al[2][2048];     // 4 x 64 x 8
    __shared__ short Bh[2][N * 32], Bl[2][N * 32]; // 4 x N x 8
    const int tid = threadIdx.x;
    const int lane = tid & 63;
    const int wave = tid >> 6;
    const int r0 = blockIdx.x * 64;

    // A staging: thread handles row=tid>>2 (0..63), k-chunk c_s=tid&3 (8 k each)
    const int row_s = tid >> 2;
    const int c_s = tid & 3;
    const float* aptr = A + (size_t)(r0 + row_s) * 256 + c_s * 8;
    const bool arow_ok = (r0 + row_s) < M;

    float4 av0, av1;
    auto issueA = [&](int kb) {
        if (arow_ok) {
            av0 = *(const float4*)(aptr + kb);
            av1 = *(const float4*)(aptr + kb + 4);
        } else {
            av0 = make_float4(0.f, 0.f, 0.f, 0.f);
            av1 = av0;
        }
    };
    auto writeA = [&](int buf) {
        float f[8] = {av0.x, av0.y, av0.z, av0.w, av1.x, av1.y, av1.z, av1.w};
        unsigned hp[4], lp[4];
        #pragma unroll
        for (int j = 0; j < 4; ++j) {
            ushort h0 = f2bf(f[2 * j]),     h1 = f2bf(f[2 * j + 1]);
            ushort l0 = f2bf(f[2 * j] - bf2f(h0));
            ushort l1 = f2bf(f[2 * j + 1] - bf2f(h1));
            hp[j] = (unsigned)h0 | ((unsigned)h1 << 16);
            lp[j] = (unsigned)l0 | ((unsigned)l1 << 16);
        }
        int idx = c_s * 512 + row_s * 8;
        *(int4*)&Ah[buf][idx] = make_int4(hp[0], hp[1], hp[2], hp[3]);
        *(int4*)&Al[buf][idx] = make_int4(lp[0], lp[1], lp[2], lp[3]);
    };
    auto issueB = [&](int buf, int t) {
        if constexpr (N == 256) {
            #pragma unroll
            for (int q = 0; q < 4; ++q) {
                const short* sh = Bph + ((size_t)(t * 4 + q) * 256 + tid) * 8;
                const short* sl = Bpl + ((size_t)(t * 4 + q) * 256 + tid) * 8;
                short* dh = &Bh[buf][q * 2048 + wave * 512];
                short* dl = &Bl[buf][q * 2048 + wave * 512];
                GLL(sh, dh);
                GLL(sl, dl);
            }
        } else {
            const short* sh = Bph + ((size_t)(t * 4 + wave) * 64 + (tid & 63)) * 8;
            const short* sl = Bpl + ((size_t)(t * 4 + wave) * 64 + (tid & 63)) * 8;
            short* dh = &Bh[buf][wave * 512];
            short* dl = &Bl[buf][wave * 512];
            GLL(sh, dh);
            GLL(sl, dl);
        }
    };

    f32x4 acc[4][FN];
    #pragma unroll
    for (int i = 0; i < 4; ++i)
        #pragma unroll
        for (int j = 0; j < FN; ++j)
            acc[i][j] = (f32x4){0.f, 0.f, 0.f, 0.f};

    const int c = lane >> 4;
    const int rs = lane & 15;
    const int wn0 = wave * (N / 4);

    issueA(0);
    issueB(0, 0);
    writeA(0);
    __syncthreads();
    int cur = 0;
    for (int t = 0; t < 8; ++t) {
        if (t < 7) {
            issueA((t + 1) * 32);
            issueB(cur ^ 1, t + 1);
        }
        // compute on buffer `cur`
        short8 ah[4], al[4];
        #pragma unroll
        for (int fm = 0; fm < 4; ++fm) {
            int idx = c * 512 + (fm * 16 + rs) * 8;
            ah[fm] = *(const short8*)&Ah[cur][idx];
            al[fm] = *(const short8*)&Al[cur][idx];
        }
        #pragma unroll
        for (int fn = 0; fn < FN; ++fn) {
            int n = wn0 + fn * 16 + rs;
            int idx = c * N * 8 + n * 8;
            short8 bhv = *(const short8*)&Bh[cur][idx];
            short8 blv = *(const short8*)&Bl[cur][idx];
            #pragma unroll
            for (int fm = 0; fm < 4; ++fm) {
                acc[fm][fn] = __builtin_amdgcn_mfma_f32_16x16x32_bf16(ah[fm], bhv, acc[fm][fn], 0, 0, 0);
                acc[fm][fn] = __builtin_amdgcn_mfma_f32_16x16x32_bf16(ah[fm], blv, acc[fm][fn], 0, 0, 0);
                acc[fm][fn] = __builtin_amdgcn_mfma_f32_16x16x32_bf16(al[fm], bhv, acc[fm][fn], 0, 0, 0);
            }
        }
        if (t < 7) writeA(cur ^ 1);
        __syncthreads();
        cur ^= 1;
    }

    // epilogue: C/D layout col=lane&15, row=(lane>>4)*4+reg
    #pragma unroll
    for (int fn = 0; fn < FN; ++fn) {
        int col = wn0 + fn * 16 + rs;
        float bv = bias ? bias[col] : 0.0f;
        #pragma unroll
        for (int fm = 0; fm < 4; ++fm) {
            #pragma unroll
            for (int g = 0; g < 4; ++g) {
                int r = r0 + fm * 16 + c * 4 + g;
                if (r < M) C[(size_t)r * N + col] = acc[fm][fn][g] + bv;
            }
        }
    }
}

// ---------------- per-node attention halves: s[n,h], d[n,h] ----------------
template<int HEADS>
__global__ __launch_bounds__(256) void sd_kernel(const float* __restrict__ h, const float* __restrict__ a_src,
                                                 const float* __restrict__ a_dst, float* __restrict__ s_out,
                                                 float* __restrict__ d_out_, int nnodes) {
    int lane = threadIdx.x & 63;
    int node = blockIdx.x * 4 + (threadIdx.x >> 6);
    if (node >= nnodes) return;
    float4 hv = *(const float4*)&h[(size_t)node * 256 + lane * 4];
    float4 as = *(const float4*)&a_src[lane * 4];
    float4 ad = *(const float4*)&a_dst[lane * 4];
    float ps = hv.x * as.x + hv.y * as.y + hv.z * as.z + hv.w * as.w;
    float pd = hv.x * ad.x + hv.y * ad.y + hv.z * ad.z + hv.w * ad.w;
    const int GS = 64 / HEADS;
    #pragma unroll
    for (int off = 1; off < GS; off <<= 1) {
        ps += __shfl_xor(ps, off);
        pd += __shfl_xor(pd, off);
    }
    int g = lane / GS;
    int r = lane & (GS - 1);
    if (r == 0) s_out[(size_t)node * HEADS + g] = ps;
    if (r == 1) d_out_[(size_t)node * HEADS + g] = pd;
}

// ---------------- fused segment-softmax + aggregate + bias + ELU ----------------
template<int HEADS>
__global__ __launch_bounds__(256) void agg_kernel(const int* __restrict__ rowptr, const int* __restrict__ csr_src,
                                                  const float* __restrict__ h, const float* __restrict__ s_att,
                                                  const float* __restrict__ d_att, const float* __restrict__ bias,
                                                  float* __restrict__ out, int nnodes) {
    int lane = threadIdx.x & 63;
    int node = blockIdx.x * 4 + (threadIdx.x >> 6);
    if (node >= nnodes) return;
    int hh = (HEADS == 8) ? (lane >> 3) : 0;
    int cbase = lane * 4;
    int begin = rowptr[node], end = rowptr[node + 1];
    float dl = d_att[(size_t)node * HEADS + hh];
    // pass 1: per-head max (unroll x4 for MLP)
    float m = -1e30f;
    int i = begin;
    for (; i + 4 <= end; i += 4) {
        int s0 = csr_src[i], s1 = csr_src[i + 1], s2 = csr_src[i + 2], s3 = csr_src[i + 3];
        float v0 = lrelu(s_att[(size_t)s0 * HEADS + hh] + dl);
        float v1 = lrelu(s_att[(size_t)s1 * HEADS + hh] + dl);
        float v2 = lrelu(s_att[(size_t)s2 * HEADS + hh] + dl);
        float v3 = lrelu(s_att[(size_t)s3 * HEADS + hh] + dl);
        m = fmaxf(m, fmaxf(fmaxf(v0, v1), fmaxf(v2, v3)));
    }
    for (; i < end; ++i) {
        int s = csr_src[i];
        m = fmaxf(m, lrelu(s_att[(size_t)s * HEADS + hh] + dl));
    }
    // pass 2: denom + weighted row gather (unroll x2, dual accumulators)
    float a0x = 0.f, a0y = 0.f, a0z = 0.f, a0w = 0.f;
    float a1x = 0.f, a1y = 0.f, a1z = 0.f, a1w = 0.f;
    float den = 0.f;
    i = begin;
    for (; i + 2 <= end; i += 2) {
        int s0 = csr_src[i], s1 = csr_src[i + 1];
        float w0 = __expf(lrelu(s_att[(size_t)s0 * HEADS + hh] + dl) - m);
        float w1 = __expf(lrelu(s_att[(size_t)s1 * HEADS + hh] + dl) - m);
        den += w0 + w1;
        float4 h0 = *(const float4*)&h[(size_t)s0 * 256 + cbase];
        float4 h1 = *(const float4*)&h[(size_t)s1 * 256 + cbase];
        a0x += w0 * h0.x; a0y += w0 * h0.y; a0z += w0 * h0.z; a0w += w0 * h0.w;
        a1x += w1 * h1.x; a1y += w1 * h1.y; a1z += w1 * h1.z; a1w += w1 * h1.w;
    }
    if (i < end) {
        int s0 = csr_src[i];
        float w0 = __expf(lrelu(s_att[(size_t)s0 * HEADS + hh] + dl) - m);
        den += w0;
        float4 h0 = *(const float4*)&h[(size_t)s0 * 256 + cbase];
        a0x += w0 * h0.x; a0y += w0 * h0.y; a0z += w0 * h0.z; a0w += w0 * h0.w;
    }
    float inv = 1.0f / den;
    float4 bv = *(const float4*)&bias[cbase];
    float4 r;
    r.x = elu_f((a0x + a1x) * inv + bv.x);
    r.y = elu_f((a0y + a1y) * inv + bv.y);
    r.z = elu_f((a0z + a1z) * inv + bv.z);
    r.w = elu_f((a0w + a1w) * inv + bv.w);
    *(float4*)&out[(size_t)node * 256 + cbase] = r;
}

extern "C" void kernel_launch(void* const* d_in, const int* in_sizes, int n_in,
                              void* d_out, int out_size, void* d_ws, size_t ws_size,
                              hipStream_t stream) {
    const float* x      = (const float*)d_in[0];
    const int*   ei     = (const int*)d_in[1];
    const float* W1     = (const float*)d_in[2];
    const float* a_src1 = (const float*)d_in[3];
    const float* a_dst1 = (const float*)d_in[4];
    const float* b1     = (const float*)d_in[5];
    const float* W2     = (const float*)d_in[6];
    const float* a_src2 = (const float*)d_in[7];
    const float* a_dst2 = (const float*)d_in[8];
    const float* b2     = (const float*)d_in[9];
    const float* Wlin   = (const float*)d_in[10];
    const float* blin   = (const float*)d_in[11];
    float* out = (float*)d_out;

    const int N = in_sizes[0] / 256;   // 50000 nodes
    const int E = in_sizes[1] / 2;     // 800000 edges
    const int ET = E + N;

    char* p = (char*)d_ws;
    auto alloc = [&](size_t bytes) {
        void* r = (void*)p;
        p += (bytes + 255) & ~size_t(255);
        return r;
    };
    float* bufA   = (float*)alloc((size_t)N * 256 * 4);
    float* bufB   = (float*)alloc((size_t)N * 256 * 4);
    float* s1     = (float*)alloc((size_t)N * 8 * 4);
    float* d1     = (float*)alloc((size_t)N * 8 * 4);
    float* s2     = (float*)alloc((size_t)N * 4);
    float* d2     = (float*)alloc((size_t)N * 4);
    int*   deg    = (int*)alloc((size_t)N * 4);
    int*   cursor = (int*)alloc((size_t)N * 4);
    int*   rowptr = (int*)alloc((size_t)(N + 1) * 4);
    int*   csr    = (int*)alloc((size_t)ET * 4);
    short* W1h    = (short*)alloc((size_t)256 * 256 * 2);
    short* W1l    = (short*)alloc((size_t)256 * 256 * 2);
    short* W2h    = (short*)alloc((size_t)256 * 256 * 2);
    short* W2l    = (short*)alloc((size_t)256 * 256 * 2);
    short* W3h    = (short*)alloc((size_t)256 * 64 * 2);
    short* W3l    = (short*)alloc((size_t)256 * 64 * 2);

    // ---- CSR build ----
    hipMemsetAsync(deg, 0, (size_t)N * 4, stream);
    hist_kernel<<<(ET + 255) / 256, 256, 0, stream>>>(ei, deg, E, N);
    scan_kernel<<<1, 1024, 0, stream>>>(deg, rowptr, cursor, N);
    scatter_kernel<<<(ET + 255) / 256, 256, 0, stream>>>(ei, cursor, csr, E, N);

    // ---- weight pre-pack ----
    wconv_kernel<<<(256 * 256 + 255) / 256, 256, 0, stream>>>(W1, W1h, W1l, 256 * 256, 256);
    wconv_kernel<<<(256 * 256 + 255) / 256, 256, 0, stream>>>(W2, W2h, W2l, 256 * 256, 256);
    wconv_kernel<<<(256 * 64 + 255) / 256, 256, 0, stream>>>(Wlin, W3h, W3l, 256 * 64, 64);

    const int gBlocks = (N + 63) / 64;
    const int nodeBlocks = (N + 3) / 4;

    // ---- layer 1 ----
    gemm_mfma<256><<<gBlocks, 256, 0, stream>>>(x, W1h, W1l, nullptr, bufA, N);
    sd_kernel<8><<<nodeBlocks, 256, 0, stream>>>(bufA, a_src1, a_dst1, s1, d1, N);
    agg_kernel<8><<<nodeBlocks, 256, 0, stream>>>(rowptr, csr, bufA, s1, d1, b1, bufB, N);

    // ---- layer 2 ----
    gemm_mfma<256><<<gBlocks, 256, 0, stream>>>(bufB, W2h, W2l, nullptr, bufA, N);
    sd_kernel<1><<<nodeBlocks, 256, 0, stream>>>(bufA, a_src2, a_dst2, s2, d2, N);
    agg_kernel<1><<<nodeBlocks, 256, 0, stream>>>(rowptr, csr, bufA, s2, d2, b2, bufB, N);

    // ---- final linear ----
    gemm_mfma<64><<<gBlocks, 256, 0, stream>>>(bufB, W3h, W3l, blin, out, N);
}

// Round 3
// 634.568 us; speedup vs baseline: 1.3903x; 1.1308x over previous
//
#include <hip/hip_runtime.h>
#include <hip/hip_bf16.h>
#include <hip/hip_fp16.h>

typedef __attribute__((ext_vector_type(8))) short short8;
typedef __attribute__((ext_vector_type(4))) float f32x4;

#define GLL(g, s) __builtin_amdgcn_global_load_lds(                        \
    (const __attribute__((address_space(1))) void*)(g),                    \
    (__attribute__((address_space(3))) void*)(s), 16, 0, 0)

__device__ __forceinline__ ushort f2bf(float f) {
    unsigned u = __float_as_uint(f);
    u += 0x7fffu + ((u >> 16) & 1u);
    return (ushort)(u >> 16);
}
__device__ __forceinline__ float bf2f(ushort h) {
    return __uint_as_float(((unsigned)h) << 16);
}
__device__ __forceinline__ float elu_f(float x) {
    return x > 0.0f ? x : expm1f(x);
}
__device__ __forceinline__ float lrelu(float x) {
    return x < 0.0f ? 0.2f * x : x;
}

// ---------------- CSR build ----------------
__global__ void hist_kernel(const int* __restrict__ ei, int* __restrict__ deg, int E, int n) {
    int total = E + n;
    for (int i = blockIdx.x * blockDim.x + threadIdx.x; i < total; i += gridDim.x * blockDim.x) {
        int d = (i < E) ? ei[E + i] : (i - E);
        atomicAdd(&deg[d], 1);
    }
}

__global__ __launch_bounds__(1024) void scan_kernel(const int* __restrict__ deg, int* __restrict__ rowptr,
                                                    int* __restrict__ cursor, int n) {
    __shared__ int part[1024];
    int t = threadIdx.x;
    int CH = (n + 1023) >> 10;
    int base = t * CH;
    int sum = 0;
    for (int j = 0; j < CH; ++j) {
        int idx = base + j;
        if (idx < n) sum += deg[idx];
    }
    part[t] = sum;
    __syncthreads();
    for (int off = 1; off < 1024; off <<= 1) {
        int v = (t >= off) ? part[t - off] : 0;
        __syncthreads();
        part[t] += v;
        __syncthreads();
    }
    int ex = (t == 0) ? 0 : part[t - 1];
    for (int j = 0; j < CH; ++j) {
        int idx = base + j;
        if (idx < n) {
            rowptr[idx] = ex;
            cursor[idx] = ex;
            ex += deg[idx];
        }
    }
    if (t == 1023) rowptr[n] = part[1023];
}

__global__ void scatter_kernel(const int* __restrict__ ei, int* __restrict__ cursor,
                               int* __restrict__ csr_src, int E, int n) {
    int total = E + n;
    for (int i = blockIdx.x * blockDim.x + threadIdx.x; i < total; i += gridDim.x * blockDim.x) {
        int s, d;
        if (i < E) { s = ei[i]; d = ei[E + i]; }
        else       { s = i - E; d = s; }
        int pos = atomicAdd(&cursor[d], 1);
        csr_src[pos] = s;
    }
}

// ---------------- W pre-pack: W[K x N] fp32 -> fragment-major bf16 hi/lo ----------------
// layout: Wp[(k/8)*N + n][k%8]
__global__ void wconv_kernel(const float* __restrict__ W, short* __restrict__ hi,
                             short* __restrict__ lo, int KN, int Ncols) {
    int idx = blockIdx.x * 256 + threadIdx.x;
    if (idx >= KN) return;
    int k = idx / Ncols, n = idx - k * Ncols;
    float v = W[idx];
    ushort h = f2bf(v);
    ushort l = f2bf(v - bf2f(h));
    size_t o = ((size_t)(k >> 3) * Ncols + n) * 8 + (k & 7);
    hi[o] = (short)h;
    lo[o] = (short)l;
}

// ---------------- split-bf16 MFMA GEMM, A-fragments direct from global ----------------
// C[M x N] = A[M x 256] @ W[256 x N] (+bias); 64-row tile, 4 waves, BK=32.
// A: per-wave register fragments (global->reg->convert, no LDS).
// B: packed hi/lo bf16 in LDS via global_load_lds, double-buffered.
template<int N, bool OUTHALF>
__global__ __launch_bounds__(256, 2) void gemm_mfma(const float* __restrict__ A,
                                                    const short* __restrict__ Bph,
                                                    const short* __restrict__ Bpl,
                                                    const float* __restrict__ bias,
                                                    void* __restrict__ Cout, int M) {
    constexpr int FN = (N == 256) ? 4 : 1;
    __shared__ short Bh[2][N * 32], Bl[2][N * 32];
    const int tid = threadIdx.x;
    const int lane = tid & 63;
    const int wave = tid >> 6;
    const int r0 = blockIdx.x * 64;
    const int c = lane >> 4;       // k-chunk of fragment (8 k each)
    const int rs = lane & 15;      // row-in-16 (A) / col-in-16 (B)
    const int wn0 = wave * (N / 4);

    // A fragment base pointers (rows clamped so last block never reads OOB)
    const float* aBase[4];
    #pragma unroll
    for (int fm = 0; fm < 4; ++fm) {
        int r = r0 + fm * 16 + rs;
        if (r > M - 1) r = M - 1;
        aBase[fm] = A + (size_t)r * 256 + c * 8;
    }

    auto issueB = [&](int buf, int t) {
        if constexpr (N == 256) {
            #pragma unroll
            for (int q = 0; q < 4; ++q) {
                const short* sh = Bph + ((size_t)(t * 4 + q) * 256 + tid) * 8;
                const short* sl = Bpl + ((size_t)(t * 4 + q) * 256 + tid) * 8;
                short* dh = &Bh[buf][q * 2048 + wave * 512];
                short* dl = &Bl[buf][q * 2048 + wave * 512];
                GLL(sh, dh);
                GLL(sl, dl);
            }
        } else {
            const short* sh = Bph + ((size_t)(t * 4 + wave) * 64 + lane) * 8;
            const short* sl = Bpl + ((size_t)(t * 4 + wave) * 64 + lane) * 8;
            short* dh = &Bh[buf][wave * 512];
            short* dl = &Bl[buf][wave * 512];
            GLL(sh, dh);
            GLL(sl, dl);
        }
    };

    float4 aregA[8], aregB[8];
    auto loadA = [&](float4* ar, int t) {
        #pragma unroll
        for (int fm = 0; fm < 4; ++fm) {
            ar[2 * fm]     = *(const float4*)(aBase[fm] + t * 32);
            ar[2 * fm + 1] = *(const float4*)(aBase[fm] + t * 32 + 4);
        }
    };
    auto convA = [&](const float4* ar, short8* ah, short8* al) {
        #pragma unroll
        for (int fm = 0; fm < 4; ++fm) {
            float f[8] = {ar[2 * fm].x, ar[2 * fm].y, ar[2 * fm].z, ar[2 * fm].w,
                          ar[2 * fm + 1].x, ar[2 * fm + 1].y, ar[2 * fm + 1].z, ar[2 * fm + 1].w};
            short8 hi, lo;
            #pragma unroll
            for (int j = 0; j < 8; ++j) {
                ushort hb = f2bf(f[j]);
                hi[j] = (short)hb;
                lo[j] = (short)f2bf(f[j] - bf2f(hb));
            }
            ah[fm] = hi;
            al[fm] = lo;
        }
    };

    f32x4 acc[4][FN];
    #pragma unroll
    for (int i = 0; i < 4; ++i)
        #pragma unroll
        for (int j = 0; j < FN; ++j)
            acc[i][j] = (f32x4){0.f, 0.f, 0.f, 0.f};

    loadA(aregA, 0);
    issueB(0, 0);
    __syncthreads();

    #pragma unroll
    for (int t = 0; t < 8; ++t) {
        float4* curA = (t & 1) ? aregB : aregA;
        float4* nxtA = (t & 1) ? aregA : aregB;
        if (t < 7) {
            loadA(nxtA, t + 1);
            issueB((t + 1) & 1, t + 1);
        }
        short8 ah[4], al[4];
        convA(curA, ah, al);
        #pragma unroll
        for (int fn = 0; fn < FN; ++fn) {
            int n = wn0 + fn * 16 + rs;
            int idx = c * N * 8 + n * 8;
            short8 bhv = *(const short8*)&Bh[t & 1][idx];
            short8 blv = *(const short8*)&Bl[t & 1][idx];
            #pragma unroll
            for (int fm = 0; fm < 4; ++fm) {
                acc[fm][fn] = __builtin_amdgcn_mfma_f32_16x16x32_bf16(ah[fm], bhv, acc[fm][fn], 0, 0, 0);
                acc[fm][fn] = __builtin_amdgcn_mfma_f32_16x16x32_bf16(ah[fm], blv, acc[fm][fn], 0, 0, 0);
                acc[fm][fn] = __builtin_amdgcn_mfma_f32_16x16x32_bf16(al[fm], bhv, acc[fm][fn], 0, 0, 0);
            }
        }
        __syncthreads();
    }

    // epilogue: C/D layout col = lane&15, row = (lane>>4)*4 + reg
    #pragma unroll
    for (int fn = 0; fn < FN; ++fn) {
        int col = wn0 + fn * 16 + rs;
        float bv = bias ? bias[col] : 0.0f;
        #pragma unroll
        for (int fm = 0; fm < 4; ++fm) {
            #pragma unroll
            for (int g = 0; g < 4; ++g) {
                int r = r0 + fm * 16 + c * 4 + g;
                if (r < M) {
                    float v = acc[fm][fn][g] + bv;
                    if constexpr (OUTHALF)
                        ((__half*)Cout)[(size_t)r * N + col] = __float2half_rn(v);
                    else
                        ((float*)Cout)[(size_t)r * N + col] = v;
                }
            }
        }
    }
}

// ---------------- per-node attention halves from fp16 h ----------------
template<int HEADS>
__global__ __launch_bounds__(256) void sd_kernel(const __half* __restrict__ h, const float* __restrict__ a_src,
                                                 const float* __restrict__ a_dst, float* __restrict__ s_out,
                                                 float* __restrict__ d_out_, int nnodes) {
    int lane = threadIdx.x & 63;
    int node = blockIdx.x * 4 + (threadIdx.x >> 6);
    if (node >= nnodes) return;
    const __half2* hp = (const __half2*)(h + (size_t)node * 256 + lane * 4);
    float2 f01 = __half22float2(hp[0]);
    float2 f23 = __half22float2(hp[1]);
    float4 as = *(const float4*)&a_src[lane * 4];
    float4 ad = *(const float4*)&a_dst[lane * 4];
    float ps = f01.x * as.x + f01.y * as.y + f23.x * as.z + f23.y * as.w;
    float pd = f01.x * ad.x + f01.y * ad.y + f23.x * ad.z + f23.y * ad.w;
    const int GS = 64 / HEADS;
    #pragma unroll
    for (int off = 1; off < GS; off <<= 1) {
        ps += __shfl_xor(ps, off);
        pd += __shfl_xor(pd, off);
    }
    int g = lane / GS;
    int r = lane & (GS - 1);
    if (r == 0) s_out[(size_t)node * HEADS + g] = ps;
    if (r == 1) d_out_[(size_t)node * HEADS + g] = pd;
}

// ---------------- fused one-pass online segment-softmax + aggregate + bias + ELU ------
// one wave per dst node; lane owns 4 contiguous channels of the fp16 h rows
template<int HEADS>
__global__ __launch_bounds__(256) void agg_kernel(const int* __restrict__ rowptr, const int* __restrict__ csr_src,
                                                  const __half* __restrict__ h, const float* __restrict__ s_att,
                                                  const float* __restrict__ d_att, const float* __restrict__ bias,
                                                  float* __restrict__ out, int nnodes) {
    int lane = threadIdx.x & 63;
    int node = blockIdx.x * 4 + (threadIdx.x >> 6);
    if (node >= nnodes) return;
    const int hh = (HEADS == 8) ? (lane >> 3) : 0;
    const int cbase = lane * 4;
    const int begin = rowptr[node], end = rowptr[node + 1];
    const float dl = d_att[(size_t)node * HEADS + hh];
    float m = -1e30f, den = 0.f;
    float ax = 0.f, ay = 0.f, az = 0.f, aw = 0.f;
    int i = begin;
    for (; i + 4 <= end; i += 4) {
        int s0 = csr_src[i], s1 = csr_src[i + 1], s2 = csr_src[i + 2], s3 = csr_src[i + 3];
        const __half2* p0 = (const __half2*)(h + (size_t)s0 * 256 + cbase);
        const __half2* p1 = (const __half2*)(h + (size_t)s1 * 256 + cbase);
        const __half2* p2 = (const __half2*)(h + (size_t)s2 * 256 + cbase);
        const __half2* p3 = (const __half2*)(h + (size_t)s3 * 256 + cbase);
        __half2 q0a = p0[0], q0b = p0[1];
        __half2 q1a = p1[0], q1b = p1[1];
        __half2 q2a = p2[0], q2b = p2[1];
        __half2 q3a = p3[0], q3b = p3[1];
        float v0 = lrelu(s_att[(size_t)s0 * HEADS + hh] + dl);
        float v1 = lrelu(s_att[(size_t)s1 * HEADS + hh] + dl);
        float v2 = lrelu(s_att[(size_t)s2 * HEADS + hh] + dl);
        float v3 = lrelu(s_att[(size_t)s3 * HEADS + hh] + dl);
        float vb = fmaxf(fmaxf(v0, v1), fmaxf(v2, v3));
        float mn = fmaxf(m, vb);
        float sc = __expf(m - mn);
        float w0 = __expf(v0 - mn), w1 = __expf(v1 - mn);
        float w2 = __expf(v2 - mn), w3 = __expf(v3 - mn);
        m = mn;
        den = den * sc + (w0 + w1) + (w2 + w3);
        float2 f0a = __half22float2(q0a), f0b = __half22float2(q0b);
        float2 f1a = __half22float2(q1a), f1b = __half22float2(q1b);
        float2 f2a = __half22float2(q2a), f2b = __half22float2(q2b);
        float2 f3a = __half22float2(q3a), f3b = __half22float2(q3b);
        ax = ax * sc + w0 * f0a.x + w1 * f1a.x + w2 * f2a.x + w3 * f3a.x;
        ay = ay * sc + w0 * f0a.y + w1 * f1a.y + w2 * f2a.y + w3 * f3a.y;
        az = az * sc + w0 * f0b.x + w1 * f1b.x + w2 * f2b.x + w3 * f3b.x;
        aw = aw * sc + w0 * f0b.y + w1 * f1b.y + w2 * f2b.y + w3 * f3b.y;
    }
    for (; i < end; ++i) {
        int s0 = csr_src[i];
        const __half2* p0 = (const __half2*)(h + (size_t)s0 * 256 + cbase);
        __half2 q0a = p0[0], q0b = p0[1];
        float v0 = lrelu(s_att[(size_t)s0 * HEADS + hh] + dl);
        float mn = fmaxf(m, v0);
        float sc = __expf(m - mn);
        float w0 = __expf(v0 - mn);
        m = mn;
        den = den * sc + w0;
        float2 f0a = __half22float2(q0a), f0b = __half22float2(q0b);
        ax = ax * sc + w0 * f0a.x;
        ay = ay * sc + w0 * f0a.y;
        az = az * sc + w0 * f0b.x;
        aw = aw * sc + w0 * f0b.y;
    }
    float inv = 1.0f / den;
    float4 bv = *(const float4*)&bias[cbase];
    float4 r;
    r.x = elu_f(ax * inv + bv.x);
    r.y = elu_f(ay * inv + bv.y);
    r.z = elu_f(az * inv + bv.z);
    r.w = elu_f(aw * inv + bv.w);
    *(float4*)&out[(size_t)node * 256 + cbase] = r;
}

extern "C" void kernel_launch(void* const* d_in, const int* in_sizes, int n_in,
                              void* d_out, int out_size, void* d_ws, size_t ws_size,
                              hipStream_t stream) {
    const float* x      = (const float*)d_in[0];
    const int*   ei     = (const int*)d_in[1];
    const float* W1     = (const float*)d_in[2];
    const float* a_src1 = (const float*)d_in[3];
    const float* a_dst1 = (const float*)d_in[4];
    const float* b1     = (const float*)d_in[5];
    const float* W2     = (const float*)d_in[6];
    const float* a_src2 = (const float*)d_in[7];
    const float* a_dst2 = (const float*)d_in[8];
    const float* b2     = (const float*)d_in[9];
    const float* Wlin   = (const float*)d_in[10];
    const float* blin   = (const float*)d_in[11];
    float* out = (float*)d_out;

    const int N = in_sizes[0] / 256;   // 50000 nodes
    const int E = in_sizes[1] / 2;     // 800000 edges
    const int ET = E + N;

    char* p = (char*)d_ws;
    auto alloc = [&](size_t bytes) {
        void* r = (void*)p;
        p += (bytes + 255) & ~size_t(255);
        return r;
    };
    __half* bufH  = (__half*)alloc((size_t)N * 256 * 2);  // fp16 h (layers 1,2)
    float* bufB   = (float*)alloc((size_t)N * 256 * 4);   // aggregated out (fp32)
    float* s1     = (float*)alloc((size_t)N * 8 * 4);
    float* d1     = (float*)alloc((size_t)N * 8 * 4);
    float* s2     = (float*)alloc((size_t)N * 4);
    float* d2     = (float*)alloc((size_t)N * 4);
    int*   deg    = (int*)alloc((size_t)N * 4);
    int*   cursor = (int*)alloc((size_t)N * 4);
    int*   rowptr = (int*)alloc((size_t)(N + 1) * 4);
    int*   csr    = (int*)alloc((size_t)ET * 4);
    short* W1h    = (short*)alloc((size_t)256 * 256 * 2);
    short* W1l    = (short*)alloc((size_t)256 * 256 * 2);
    short* W2h    = (short*)alloc((size_t)256 * 256 * 2);
    short* W2l    = (short*)alloc((size_t)256 * 256 * 2);
    short* W3h    = (short*)alloc((size_t)256 * 64 * 2);
    short* W3l    = (short*)alloc((size_t)256 * 64 * 2);

    // ---- CSR build ----
    hipMemsetAsync(deg, 0, (size_t)N * 4, stream);
    hist_kernel<<<(ET + 255) / 256, 256, 0, stream>>>(ei, deg, E, N);
    scan_kernel<<<1, 1024, 0, stream>>>(deg, rowptr, cursor, N);
    scatter_kernel<<<(ET + 255) / 256, 256, 0, stream>>>(ei, cursor, csr, E, N);

    // ---- weight pre-pack ----
    wconv_kernel<<<(256 * 256 + 255) / 256, 256, 0, stream>>>(W1, W1h, W1l, 256 * 256, 256);
    wconv_kernel<<<(256 * 256 + 255) / 256, 256, 0, stream>>>(W2, W2h, W2l, 256 * 256, 256);
    wconv_kernel<<<(256 * 64 + 255) / 256, 256, 0, stream>>>(Wlin, W3h, W3l, 256 * 64, 64);

    const int gBlocks = (N + 63) / 64;
    const int nodeBlocks = (N + 3) / 4;

    // ---- layer 1 ----
    gemm_mfma<256, true><<<gBlocks, 256, 0, stream>>>(x, W1h, W1l, nullptr, bufH, N);
    sd_kernel<8><<<nodeBlocks, 256, 0, stream>>>(bufH, a_src1, a_dst1, s1, d1, N);
    agg_kernel<8><<<nodeBlocks, 256, 0, stream>>>(rowptr, csr, bufH, s1, d1, b1, bufB, N);

    // ---- layer 2 ----
    gemm_mfma<256, true><<<gBlocks, 256, 0, stream>>>(bufB, W2h, W2l, nullptr, bufH, N);
    sd_kernel<1><<<nodeBlocks, 256, 0, stream>>>(bufH, a_src2, a_dst2, s2, d2, N);
    agg_kernel<1><<<nodeBlocks, 256, 0, stream>>>(rowptr, csr, bufH, s2, d2, b2, bufB, N);

    // ---- final linear ----
    gemm_mfma<64, false><<<gBlocks, 256, 0, stream>>>(bufB, W3h, W3l, blin, out, N);
}

// Round 4
// 518.798 us; speedup vs baseline: 1.7006x; 1.2231x over previous
//
#include <hip/hip_runtime.h>
#include <hip/hip_bf16.h>
#include <hip/hip_fp16.h>

typedef __attribute__((ext_vector_type(8))) short short8;
typedef __attribute__((ext_vector_type(4))) float f32x4;

#define GLL(g, s) __builtin_amdgcn_global_load_lds(                        \
    (const __attribute__((address_space(1))) void*)(g),                    \
    (__attribute__((address_space(3))) void*)(s), 16, 0, 0)

__device__ __forceinline__ ushort f2bf(float f) {
    unsigned u = __float_as_uint(f);
    u += 0x7fffu + ((u >> 16) & 1u);
    return (ushort)(u >> 16);
}
__device__ __forceinline__ float bf2f(ushort h) {
    return __uint_as_float(((unsigned)h) << 16);
}
__device__ __forceinline__ float elu_f(float x) {
    return x > 0.0f ? x : expm1f(x);
}
__device__ __forceinline__ float lrelu(float x) {
    return x < 0.0f ? 0.2f * x : x;
}

// ---------------- CSR build ----------------
__global__ void hist_kernel(const int* __restrict__ ei, int* __restrict__ deg, int E, int n) {
    int total = E + n;
    for (int i = blockIdx.x * blockDim.x + threadIdx.x; i < total; i += gridDim.x * blockDim.x) {
        int d = (i < E) ? ei[E + i] : (i - E);
        atomicAdd(&deg[d], 1);
    }
}

// phase 1: per-256-chunk sums
__global__ __launch_bounds__(256) void partial_kernel(const int* __restrict__ deg, int* __restrict__ bsums, int n) {
    __shared__ int sm[256];
    int t = threadIdx.x;
    int idx = blockIdx.x * 256 + t;
    sm[t] = (idx < n) ? deg[idx] : 0;
    __syncthreads();
    #pragma unroll
    for (int off = 128; off > 0; off >>= 1) {
        if (t < off) sm[t] += sm[t + off];
        __syncthreads();
    }
    if (t == 0) bsums[blockIdx.x] = sm[0];
}

// phase 2: scan block sums (single small block), carry loop handles nb>256
__global__ __launch_bounds__(256) void scanblocks_kernel(const int* __restrict__ bsums, int* __restrict__ boff,
                                                         int* __restrict__ rowptr, int nb, int n) {
    __shared__ int sm[256];
    int t = threadIdx.x;
    int carry = 0;
    for (int base = 0; base < nb; base += 256) {
        int i = base + t;
        int v = (i < nb) ? bsums[i] : 0;
        sm[t] = v;
        __syncthreads();
        #pragma unroll
        for (int off = 1; off < 256; off <<= 1) {
            int x = (t >= off) ? sm[t - off] : 0;
            __syncthreads();
            sm[t] += x;
            __syncthreads();
        }
        if (i < nb) boff[i] = carry + sm[t] - v;
        int tot = sm[255];
        __syncthreads();
        carry += tot;
    }
    if (t == 0) rowptr[n] = carry;
}

// phase 3: block-local exclusive scan + offset -> rowptr & cursor
__global__ __launch_bounds__(256) void finalize_kernel(const int* __restrict__ deg, const int* __restrict__ boff,
                                                       int* __restrict__ rowptr, int* __restrict__ cursor, int n) {
    __shared__ int sm[256];
    int t = threadIdx.x;
    int idx = blockIdx.x * 256 + t;
    int v = (idx < n) ? deg[idx] : 0;
    sm[t] = v;
    __syncthreads();
    #pragma unroll
    for (int off = 1; off < 256; off <<= 1) {
        int x = (t >= off) ? sm[t - off] : 0;
        __syncthreads();
        sm[t] += x;
        __syncthreads();
    }
    if (idx < n) {
        int ex = boff[blockIdx.x] + sm[t] - v;
        rowptr[idx] = ex;
        cursor[idx] = ex;
    }
}

__global__ void scatter_kernel(const int* __restrict__ ei, int* __restrict__ cursor,
                               int* __restrict__ csr_src, int E, int n) {
    int total = E + n;
    for (int i = blockIdx.x * blockDim.x + threadIdx.x; i < total; i += gridDim.x * blockDim.x) {
        int s, d;
        if (i < E) { s = ei[i]; d = ei[E + i]; }
        else       { s = i - E; d = s; }
        int pos = atomicAdd(&cursor[d], 1);
        csr_src[pos] = s;
    }
}

// ---------------- W pre-pack: W[K x N] fp32 -> fragment-major bf16 hi/lo ----------------
__global__ void wconv_kernel(const float* __restrict__ W, short* __restrict__ hi,
                             short* __restrict__ lo, int KN, int Ncols) {
    int idx = blockIdx.x * 256 + threadIdx.x;
    if (idx >= KN) return;
    int k = idx / Ncols, n = idx - k * Ncols;
    float v = W[idx];
    ushort h = f2bf(v);
    ushort l = f2bf(v - bf2f(h));
    size_t o = ((size_t)(k >> 3) * Ncols + n) * 8 + (k & 7);
    hi[o] = (short)h;
    lo[o] = (short)l;
}

// ---------------- split-bf16 MFMA GEMM, A-fragments direct from global ----------------
template<int N, bool OUTHALF>
__global__ __launch_bounds__(256, 2) void gemm_mfma(const float* __restrict__ A,
                                                    const short* __restrict__ Bph,
                                                    const short* __restrict__ Bpl,
                                                    const float* __restrict__ bias,
                                                    void* __restrict__ Cout, int M) {
    constexpr int FN = (N == 256) ? 4 : 1;
    __shared__ short Bh[2][N * 32], Bl[2][N * 32];
    const int tid = threadIdx.x;
    const int lane = tid & 63;
    const int wave = tid >> 6;
    const int r0 = blockIdx.x * 64;
    const int c = lane >> 4;
    const int rs = lane & 15;
    const int wn0 = wave * (N / 4);

    const float* aBase[4];
    #pragma unroll
    for (int fm = 0; fm < 4; ++fm) {
        int r = r0 + fm * 16 + rs;
        if (r > M - 1) r = M - 1;
        aBase[fm] = A + (size_t)r * 256 + c * 8;
    }

    auto issueB = [&](int buf, int t) {
        if constexpr (N == 256) {
            #pragma unroll
            for (int q = 0; q < 4; ++q) {
                const short* sh = Bph + ((size_t)(t * 4 + q) * 256 + tid) * 8;
                const short* sl = Bpl + ((size_t)(t * 4 + q) * 256 + tid) * 8;
                short* dh = &Bh[buf][q * 2048 + wave * 512];
                short* dl = &Bl[buf][q * 2048 + wave * 512];
                GLL(sh, dh);
                GLL(sl, dl);
            }
        } else {
            const short* sh = Bph + ((size_t)(t * 4 + wave) * 64 + lane) * 8;
            const short* sl = Bpl + ((size_t)(t * 4 + wave) * 64 + lane) * 8;
            short* dh = &Bh[buf][wave * 512];
            short* dl = &Bl[buf][wave * 512];
            GLL(sh, dh);
            GLL(sl, dl);
        }
    };

    float4 aregA[8], aregB[8];
    auto loadA = [&](float4* ar, int t) {
        #pragma unroll
        for (int fm = 0; fm < 4; ++fm) {
            ar[2 * fm]     = *(const float4*)(aBase[fm] + t * 32);
            ar[2 * fm + 1] = *(const float4*)(aBase[fm] + t * 32 + 4);
        }
    };
    auto convA = [&](const float4* ar, short8* ah, short8* al) {
        #pragma unroll
        for (int fm = 0; fm < 4; ++fm) {
            float f[8] = {ar[2 * fm].x, ar[2 * fm].y, ar[2 * fm].z, ar[2 * fm].w,
                          ar[2 * fm + 1].x, ar[2 * fm + 1].y, ar[2 * fm + 1].z, ar[2 * fm + 1].w};
            short8 hi, lo;
            #pragma unroll
            for (int j = 0; j < 8; ++j) {
                ushort hb = f2bf(f[j]);
                hi[j] = (short)hb;
                lo[j] = (short)f2bf(f[j] - bf2f(hb));
            }
            ah[fm] = hi;
            al[fm] = lo;
        }
    };

    f32x4 acc[4][FN];
    #pragma unroll
    for (int i = 0; i < 4; ++i)
        #pragma unroll
        for (int j = 0; j < FN; ++j)
            acc[i][j] = (f32x4){0.f, 0.f, 0.f, 0.f};

    loadA(aregA, 0);
    issueB(0, 0);
    __syncthreads();

    #pragma unroll
    for (int t = 0; t < 8; ++t) {
        float4* curA = (t & 1) ? aregB : aregA;
        float4* nxtA = (t & 1) ? aregA : aregB;
        if (t < 7) {
            loadA(nxtA, t + 1);
            issueB((t + 1) & 1, t + 1);
        }
        short8 ah[4], al[4];
        convA(curA, ah, al);
        #pragma unroll
        for (int fn = 0; fn < FN; ++fn) {
            int n = wn0 + fn * 16 + rs;
            int idx = c * N * 8 + n * 8;
            short8 bhv = *(const short8*)&Bh[t & 1][idx];
            short8 blv = *(const short8*)&Bl[t & 1][idx];
            #pragma unroll
            for (int fm = 0; fm < 4; ++fm) {
                acc[fm][fn] = __builtin_amdgcn_mfma_f32_16x16x32_bf16(ah[fm], bhv, acc[fm][fn], 0, 0, 0);
                acc[fm][fn] = __builtin_amdgcn_mfma_f32_16x16x32_bf16(ah[fm], blv, acc[fm][fn], 0, 0, 0);
                acc[fm][fn] = __builtin_amdgcn_mfma_f32_16x16x32_bf16(al[fm], bhv, acc[fm][fn], 0, 0, 0);
            }
        }
        __syncthreads();
    }

    #pragma unroll
    for (int fn = 0; fn < FN; ++fn) {
        int col = wn0 + fn * 16 + rs;
        float bv = bias ? bias[col] : 0.0f;
        #pragma unroll
        for (int fm = 0; fm < 4; ++fm) {
            #pragma unroll
            for (int g = 0; g < 4; ++g) {
                int r = r0 + fm * 16 + c * 4 + g;
                if (r < M) {
                    float v = acc[fm][fn][g] + bv;
                    if constexpr (OUTHALF)
                        ((__half*)Cout)[(size_t)r * N + col] = __float2half_rn(v);
                    else
                        ((float*)Cout)[(size_t)r * N + col] = v;
                }
            }
        }
    }
}

// ---------------- per-node attention halves from fp16 h ----------------
template<int HEADS>
__global__ __launch_bounds__(256) void sd_kernel(const __half* __restrict__ h, const float* __restrict__ a_src,
                                                 const float* __restrict__ a_dst, float* __restrict__ s_out,
                                                 float* __restrict__ d_out_, int nnodes) {
    int lane = threadIdx.x & 63;
    int node = blockIdx.x * 4 + (threadIdx.x >> 6);
    if (node >= nnodes) return;
    const __half2* hp = (const __half2*)(h + (size_t)node * 256 + lane * 4);
    float2 f01 = __half22float2(hp[0]);
    float2 f23 = __half22float2(hp[1]);
    float4 as = *(const float4*)&a_src[lane * 4];
    float4 ad = *(const float4*)&a_dst[lane * 4];
    float ps = f01.x * as.x + f01.y * as.y + f23.x * as.z + f23.y * as.w;
    float pd = f01.x * ad.x + f01.y * ad.y + f23.x * ad.z + f23.y * ad.w;
    const int GS = 64 / HEADS;
    #pragma unroll
    for (int off = 1; off < GS; off <<= 1) {
        ps += __shfl_xor(ps, off);
        pd += __shfl_xor(pd, off);
    }
    int g = lane / GS;
    int r = lane & (GS - 1);
    if (r == 0) s_out[(size_t)node * HEADS + g] = ps;
    if (r == 1) d_out_[(size_t)node * HEADS + g] = pd;
}

// ---------------- fused one-pass online segment-softmax + aggregate + bias + ELU ------
template<int HEADS>
__global__ __launch_bounds__(256) void agg_kernel(const int* __restrict__ rowptr, const int* __restrict__ csr_src,
                                                  const __half* __restrict__ h, const float* __restrict__ s_att,
                                                  const float* __restrict__ d_att, const float* __restrict__ bias,
                                                  float* __restrict__ out, int nnodes) {
    int lane = threadIdx.x & 63;
    int node = blockIdx.x * 4 + (threadIdx.x >> 6);
    if (node >= nnodes) return;
    const int hh = (HEADS == 8) ? (lane >> 3) : 0;
    const int cbase = lane * 4;
    const int begin = rowptr[node], end = rowptr[node + 1];
    const float dl = d_att[(size_t)node * HEADS + hh];
    float m = -1e30f, den = 0.f;
    float ax = 0.f, ay = 0.f, az = 0.f, aw = 0.f;
    int i = begin;
    for (; i + 4 <= end; i += 4) {
        int s0 = csr_src[i], s1 = csr_src[i + 1], s2 = csr_src[i + 2], s3 = csr_src[i + 3];
        const __half2* p0 = (const __half2*)(h + (size_t)s0 * 256 + cbase);
        const __half2* p1 = (const __half2*)(h + (size_t)s1 * 256 + cbase);
        const __half2* p2 = (const __half2*)(h + (size_t)s2 * 256 + cbase);
        const __half2* p3 = (const __half2*)(h + (size_t)s3 * 256 + cbase);
        __half2 q0a = p0[0], q0b = p0[1];
        __half2 q1a = p1[0], q1b = p1[1];
        __half2 q2a = p2[0], q2b = p2[1];
        __half2 q3a = p3[0], q3b = p3[1];
        float v0 = lrelu(s_att[(size_t)s0 * HEADS + hh] + dl);
        float v1 = lrelu(s_att[(size_t)s1 * HEADS + hh] + dl);
        float v2 = lrelu(s_att[(size_t)s2 * HEADS + hh] + dl);
        float v3 = lrelu(s_att[(size_t)s3 * HEADS + hh] + dl);
        float vb = fmaxf(fmaxf(v0, v1), fmaxf(v2, v3));
        float mn = fmaxf(m, vb);
        float sc = __expf(m - mn);
        float w0 = __expf(v0 - mn), w1 = __expf(v1 - mn);
        float w2 = __expf(v2 - mn), w3 = __expf(v3 - mn);
        m = mn;
        den = den * sc + (w0 + w1) + (w2 + w3);
        float2 f0a = __half22float2(q0a), f0b = __half22float2(q0b);
        float2 f1a = __half22float2(q1a), f1b = __half22float2(q1b);
        float2 f2a = __half22float2(q2a), f2b = __half22float2(q2b);
        float2 f3a = __half22float2(q3a), f3b = __half22float2(q3b);
        ax = ax * sc + w0 * f0a.x + w1 * f1a.x + w2 * f2a.x + w3 * f3a.x;
        ay = ay * sc + w0 * f0a.y + w1 * f1a.y + w2 * f2a.y + w3 * f3a.y;
        az = az * sc + w0 * f0b.x + w1 * f1b.x + w2 * f2b.x + w3 * f3b.x;
        aw = aw * sc + w0 * f0b.y + w1 * f1b.y + w2 * f2b.y + w3 * f3b.y;
    }
    for (; i < end; ++i) {
        int s0 = csr_src[i];
        const __half2* p0 = (const __half2*)(h + (size_t)s0 * 256 + cbase);
        __half2 q0a = p0[0], q0b = p0[1];
        float v0 = lrelu(s_att[(size_t)s0 * HEADS + hh] + dl);
        float mn = fmaxf(m, v0);
        float sc = __expf(m - mn);
        float w0 = __expf(v0 - mn);
        m = mn;
        den = den * sc + w0;
        float2 f0a = __half22float2(q0a), f0b = __half22float2(q0b);
        ax = ax * sc + w0 * f0a.x;
        ay = ay * sc + w0 * f0a.y;
        az = az * sc + w0 * f0b.x;
        aw = aw * sc + w0 * f0b.y;
    }
    float inv = 1.0f / den;
    float4 bv = *(const float4*)&bias[cbase];
    float4 r;
    r.x = elu_f(ax * inv + bv.x);
    r.y = elu_f(ay * inv + bv.y);
    r.z = elu_f(az * inv + bv.z);
    r.w = elu_f(aw * inv + bv.w);
    *(float4*)&out[(size_t)node * 256 + cbase] = r;
}

extern "C" void kernel_launch(void* const* d_in, const int* in_sizes, int n_in,
                              void* d_out, int out_size, void* d_ws, size_t ws_size,
                              hipStream_t stream) {
    const float* x      = (const float*)d_in[0];
    const int*   ei     = (const int*)d_in[1];
    const float* W1     = (const float*)d_in[2];
    const float* a_src1 = (const float*)d_in[3];
    const float* a_dst1 = (const float*)d_in[4];
    const float* b1     = (const float*)d_in[5];
    const float* W2     = (const float*)d_in[6];
    const float* a_src2 = (const float*)d_in[7];
    const float* a_dst2 = (const float*)d_in[8];
    const float* b2     = (const float*)d_in[9];
    const float* Wlin   = (const float*)d_in[10];
    const float* blin   = (const float*)d_in[11];
    float* out = (float*)d_out;

    const int N = in_sizes[0] / 256;   // 50000 nodes
    const int E = in_sizes[1] / 2;     // 800000 edges
    const int ET = E + N;
    const int NB = (N + 255) / 256;    // scan blocks

    char* p = (char*)d_ws;
    auto alloc = [&](size_t bytes) {
        void* r = (void*)p;
        p += (bytes + 255) & ~size_t(255);
        return r;
    };
    __half* bufH  = (__half*)alloc((size_t)N * 256 * 2);
    float* bufB   = (float*)alloc((size_t)N * 256 * 4);
    float* s1     = (float*)alloc((size_t)N * 8 * 4);
    float* d1     = (float*)alloc((size_t)N * 8 * 4);
    float* s2     = (float*)alloc((size_t)N * 4);
    float* d2     = (float*)alloc((size_t)N * 4);
    int*   deg    = (int*)alloc((size_t)N * 4);
    int*   cursor = (int*)alloc((size_t)N * 4);
    int*   rowptr = (int*)alloc((size_t)(N + 1) * 4);
    int*   csr    = (int*)alloc((size_t)ET * 4);
    int*   bsums  = (int*)alloc((size_t)NB * 4);
    int*   boff   = (int*)alloc((size_t)NB * 4);
    short* W1h    = (short*)alloc((size_t)256 * 256 * 2);
    short* W1l    = (short*)alloc((size_t)256 * 256 * 2);
    short* W2h    = (short*)alloc((size_t)256 * 256 * 2);
    short* W2l    = (short*)alloc((size_t)256 * 256 * 2);
    short* W3h    = (short*)alloc((size_t)256 * 64 * 2);
    short* W3l    = (short*)alloc((size_t)256 * 64 * 2);

    // ---- CSR build (parallel scan) ----
    hipMemsetAsync(deg, 0, (size_t)N * 4, stream);
    hist_kernel<<<(ET + 255) / 256, 256, 0, stream>>>(ei, deg, E, N);
    partial_kernel<<<NB, 256, 0, stream>>>(deg, bsums, N);
    scanblocks_kernel<<<1, 256, 0, stream>>>(bsums, boff, rowptr, NB, N);
    finalize_kernel<<<NB, 256, 0, stream>>>(deg, boff, rowptr, cursor, N);
    scatter_kernel<<<(ET + 255) / 256, 256, 0, stream>>>(ei, cursor, csr, E, N);

    // ---- weight pre-pack ----
    wconv_kernel<<<(256 * 256 + 255) / 256, 256, 0, stream>>>(W1, W1h, W1l, 256 * 256, 256);
    wconv_kernel<<<(256 * 256 + 255) / 256, 256, 0, stream>>>(W2, W2h, W2l, 256 * 256, 256);
    wconv_kernel<<<(256 * 64 + 255) / 256, 256, 0, stream>>>(Wlin, W3h, W3l, 256 * 64, 64);

    const int gBlocks = (N + 63) / 64;
    const int nodeBlocks = (N + 3) / 4;

    // ---- layer 1 ----
    gemm_mfma<256, true><<<gBlocks, 256, 0, stream>>>(x, W1h, W1l, nullptr, bufH, N);
    sd_kernel<8><<<nodeBlocks, 256, 0, stream>>>(bufH, a_src1, a_dst1, s1, d1, N);
    agg_kernel<8><<<nodeBlocks, 256, 0, stream>>>(rowptr, csr, bufH, s1, d1, b1, bufB, N);

    // ---- layer 2 ----
    gemm_mfma<256, true><<<gBlocks, 256, 0, stream>>>(bufB, W2h, W2l, nullptr, bufH, N);
    sd_kernel<1><<<nodeBlocks, 256, 0, stream>>>(bufH, a_src2, a_dst2, s2, d2, N);
    agg_kernel<1><<<nodeBlocks, 256, 0, stream>>>(rowptr, csr, bufH, s2, d2, b2, bufB, N);

    // ---- final linear ----
    gemm_mfma<64, false><<<gBlocks, 256, 0, stream>>>(bufB, W3h, W3l, blin, out, N);
}

// Round 5
// 517.436 us; speedup vs baseline: 1.7051x; 1.0026x over previous
//
#include <hip/hip_runtime.h>
#include <hip/hip_bf16.h>
#include <hip/hip_fp16.h>

typedef __attribute__((ext_vector_type(8))) short short8;
typedef __attribute__((ext_vector_type(4))) float f32x4;

#define GLL(g, s) __builtin_amdgcn_global_load_lds(                        \
    (const __attribute__((address_space(1))) void*)(g),                    \
    (__attribute__((address_space(3))) void*)(s), 16, 0, 0)

__device__ __forceinline__ ushort f2bf(float f) {
    unsigned u = __float_as_uint(f);
    u += 0x7fffu + ((u >> 16) & 1u);
    return (ushort)(u >> 16);
}
__device__ __forceinline__ float bf2f(ushort h) {
    return __uint_as_float(((unsigned)h) << 16);
}
__device__ __forceinline__ float elu_f(float x) {
    return x > 0.0f ? x : expm1f(x);
}
__device__ __forceinline__ float lrelu(float x) {
    return x < 0.0f ? 0.2f * x : x;
}

// ---------------- CSR build ----------------
__global__ void hist_kernel(const int* __restrict__ ei, int* __restrict__ deg, int E, int n) {
    int total = E + n;
    for (int i = blockIdx.x * blockDim.x + threadIdx.x; i < total; i += gridDim.x * blockDim.x) {
        int d = (i < E) ? ei[E + i] : (i - E);
        atomicAdd(&deg[d], 1);
    }
}

__global__ __launch_bounds__(256) void partial_kernel(const int* __restrict__ deg, int* __restrict__ bsums, int n) {
    __shared__ int sm[256];
    int t = threadIdx.x;
    int idx = blockIdx.x * 256 + t;
    sm[t] = (idx < n) ? deg[idx] : 0;
    __syncthreads();
    #pragma unroll
    for (int off = 128; off > 0; off >>= 1) {
        if (t < off) sm[t] += sm[t + off];
        __syncthreads();
    }
    if (t == 0) bsums[blockIdx.x] = sm[0];
}

__global__ __launch_bounds__(256) void scanblocks_kernel(const int* __restrict__ bsums, int* __restrict__ boff,
                                                         int* __restrict__ rowptr, int nb, int n) {
    __shared__ int sm[256];
    int t = threadIdx.x;
    int carry = 0;
    for (int base = 0; base < nb; base += 256) {
        int i = base + t;
        int v = (i < nb) ? bsums[i] : 0;
        sm[t] = v;
        __syncthreads();
        #pragma unroll
        for (int off = 1; off < 256; off <<= 1) {
            int x = (t >= off) ? sm[t - off] : 0;
            __syncthreads();
            sm[t] += x;
            __syncthreads();
        }
        if (i < nb) boff[i] = carry + sm[t] - v;
        int tot = sm[255];
        __syncthreads();
        carry += tot;
    }
    if (t == 0) rowptr[n] = carry;
}

__global__ __launch_bounds__(256) void finalize_kernel(const int* __restrict__ deg, const int* __restrict__ boff,
                                                       int* __restrict__ rowptr, int* __restrict__ cursor, int n) {
    __shared__ int sm[256];
    int t = threadIdx.x;
    int idx = blockIdx.x * 256 + t;
    int v = (idx < n) ? deg[idx] : 0;
    sm[t] = v;
    __syncthreads();
    #pragma unroll
    for (int off = 1; off < 256; off <<= 1) {
        int x = (t >= off) ? sm[t - off] : 0;
        __syncthreads();
        sm[t] += x;
        __syncthreads();
    }
    if (idx < n) {
        int ex = boff[blockIdx.x] + sm[t] - v;
        rowptr[idx] = ex;
        cursor[idx] = ex;
    }
}

__global__ void scatter_kernel(const int* __restrict__ ei, int* __restrict__ cursor,
                               int* __restrict__ csr_src, int E, int n) {
    int total = E + n;
    for (int i = blockIdx.x * blockDim.x + threadIdx.x; i < total; i += gridDim.x * blockDim.x) {
        int s, d;
        if (i < E) { s = ei[i]; d = ei[E + i]; }
        else       { s = i - E; d = s; }
        int pos = atomicAdd(&cursor[d], 1);
        csr_src[pos] = s;
    }
}

// ---------------- W pre-pack: W[K x N] fp32 -> fragment-major bf16 hi/lo ----------------
__global__ void wconv_kernel(const float* __restrict__ W, short* __restrict__ hi,
                             short* __restrict__ lo, int KN, int Ncols) {
    int idx = blockIdx.x * 256 + threadIdx.x;
    if (idx >= KN) return;
    int k = idx / Ncols, n = idx - k * Ncols;
    float v = W[idx];
    ushort h = f2bf(v);
    ushort l = f2bf(v - bf2f(h));
    size_t o = ((size_t)(k >> 3) * Ncols + n) * 8 + (k & 7);
    hi[o] = (short)h;
    lo[o] = (short)l;
}

// ---------------- barrier-free split-bf16 MFMA GEMM ----------------
// C[M x N] = A[M x 256] @ W[256 x N] (+bias); 64-row tile, 4 waves, BK=32.
// Each wave owns a PRIVATE LDS region for its B-slice: it writes it via
// global_load_lds and is the only reader -> no __syncthreads anywhere.
// Pipeline: 2 batches (A-regs + B-GLL, 16 vmem ops each) in flight, advanced
// with counted s_waitcnt vmcnt(16) (never a full drain until the last step).
template<int N, bool OUTHALF>
__global__ __launch_bounds__(256, 2) void gemm_mfma(const float* __restrict__ A,
                                                    const short* __restrict__ Bph,
                                                    const short* __restrict__ Bpl,
                                                    const float* __restrict__ bias,
                                                    void* __restrict__ Cout, int M) {
    constexpr int FN = (N == 256) ? 4 : 1;
    // wave-private: [wave][buf][kchunk q][64 cols][8 k] (each q-slab = 1KB = one GLL)
    __shared__ short Bh[4][2][4][64][8];   // 32 KB
    __shared__ short Bl[4][2][4][64][8];   // 32 KB
    const int tid = threadIdx.x;
    const int lane = tid & 63;
    const int wave = tid >> 6;
    const int r0 = blockIdx.x * 64;
    const int c = lane >> 4;       // k-chunk of fragment (8 k each)
    const int rs = lane & 15;      // row-in-16 (A) / col-in-16 (B)
    const int c0 = (N == 256) ? wave * 64 : 0;   // wave's global col base for staging
    const int colin = (N == 256) ? rs : (wave * 16 + rs);  // col within wave's slice (for fn=0)

    const float* aBase[4];
    #pragma unroll
    for (int fm = 0; fm < 4; ++fm) {
        int r = r0 + fm * 16 + rs;
        if (r > M - 1) r = M - 1;
        aBase[fm] = A + (size_t)r * 256 + c * 8;
    }

    // one batch = 8 global_load_dwordx4 (A) + 8 global_load_lds (B) = 16 vmem ops
    float4 aregA[8], aregB[8];
    auto loadA = [&](float4* ar, int t) {
        #pragma unroll
        for (int fm = 0; fm < 4; ++fm) {
            ar[2 * fm]     = *(const float4*)(aBase[fm] + t * 32);
            ar[2 * fm + 1] = *(const float4*)(aBase[fm] + t * 32 + 4);
        }
    };
    auto issueB = [&](int buf, int t) {
        #pragma unroll
        for (int q = 0; q < 4; ++q) {
            const short* sh = Bph + ((size_t)(t * 4 + q) * N + c0 + lane) * 8;
            const short* sl = Bpl + ((size_t)(t * 4 + q) * N + c0 + lane) * 8;
            GLL(sh, &Bh[wave][buf][q][0][0]);   // lane l -> col slot l (16B)
            GLL(sl, &Bl[wave][buf][q][0][0]);
        }
    };
    auto convA = [&](const float4* ar, short8* ah, short8* al) {
        #pragma unroll
        for (int fm = 0; fm < 4; ++fm) {
            float f[8] = {ar[2 * fm].x, ar[2 * fm].y, ar[2 * fm].z, ar[2 * fm].w,
                          ar[2 * fm + 1].x, ar[2 * fm + 1].y, ar[2 * fm + 1].z, ar[2 * fm + 1].w};
            short8 hi, lo;
            #pragma unroll
            for (int j = 0; j < 8; ++j) {
                ushort hb = f2bf(f[j]);
                hi[j] = (short)hb;
                lo[j] = (short)f2bf(f[j] - bf2f(hb));
            }
            ah[fm] = hi;
            al[fm] = lo;
        }
    };

    f32x4 acc[4][FN];
    #pragma unroll
    for (int i = 0; i < 4; ++i)
        #pragma unroll
        for (int j = 0; j < FN; ++j)
            acc[i][j] = (f32x4){0.f, 0.f, 0.f, 0.f};

    // prologue: two batches in flight (32 vmem ops)
    loadA(aregA, 0); issueB(0, 0);
    loadA(aregB, 1); issueB(1, 1);

    #pragma unroll
    for (int t = 0; t < 8; ++t) {
        // batch t complete; batch t+1 (16 ops) stays in flight
        if (t < 7) asm volatile("s_waitcnt vmcnt(16)" ::: "memory");
        else       asm volatile("s_waitcnt vmcnt(0)" ::: "memory");
        const int cur = t & 1;
        const float4* curA = (t & 1) ? aregB : aregA;
        short8 ah[4], al[4];
        convA(curA, ah, al);
        #pragma unroll
        for (int fn = 0; fn < FN; ++fn) {
            short8 bhv = *(const short8*)&Bh[wave][cur][c][colin + fn * 16][0];
            short8 blv = *(const short8*)&Bl[wave][cur][c][colin + fn * 16][0];
            #pragma unroll
            for (int fm = 0; fm < 4; ++fm) {
                acc[fm][fn] = __builtin_amdgcn_mfma_f32_16x16x32_bf16(ah[fm], bhv, acc[fm][fn], 0, 0, 0);
                acc[fm][fn] = __builtin_amdgcn_mfma_f32_16x16x32_bf16(ah[fm], blv, acc[fm][fn], 0, 0, 0);
                acc[fm][fn] = __builtin_amdgcn_mfma_f32_16x16x32_bf16(al[fm], bhv, acc[fm][fn], 0, 0, 0);
            }
        }
        // ds_reads of buf cur are complete (MFMA operand waits); fence before reuse
        asm volatile("s_waitcnt lgkmcnt(0)" ::: "memory");
        if (t < 6) {
            float4* nxtA = (t & 1) ? aregB : aregA;   // parity t consumed above
            loadA(nxtA, t + 2);
            issueB(cur, t + 2);
        }
    }

    // epilogue: C/D layout col = lane&15, row = (lane>>4)*4 + reg
    const int wn0 = wave * (N / 4);
    #pragma unroll
    for (int fn = 0; fn < FN; ++fn) {
        int col = wn0 + fn * 16 + rs;
        float bv = bias ? bias[col] : 0.0f;
        #pragma unroll
        for (int fm = 0; fm < 4; ++fm) {
            #pragma unroll
            for (int g = 0; g < 4; ++g) {
                int r = r0 + fm * 16 + c * 4 + g;
                if (r < M) {
                    float v = acc[fm][fn][g] + bv;
                    if constexpr (OUTHALF)
                        ((__half*)Cout)[(size_t)r * N + col] = __float2half_rn(v);
                    else
                        ((float*)Cout)[(size_t)r * N + col] = v;
                }
            }
        }
    }
}

// ---------------- per-node attention halves from fp16 h ----------------
template<int HEADS>
__global__ __launch_bounds__(256) void sd_kernel(const __half* __restrict__ h, const float* __restrict__ a_src,
                                                 const float* __restrict__ a_dst, float* __restrict__ s_out,
                                                 float* __restrict__ d_out_, int nnodes) {
    int lane = threadIdx.x & 63;
    int node = blockIdx.x * 4 + (threadIdx.x >> 6);
    if (node >= nnodes) return;
    const __half2* hp = (const __half2*)(h + (size_t)node * 256 + lane * 4);
    float2 f01 = __half22float2(hp[0]);
    float2 f23 = __half22float2(hp[1]);
    float4 as = *(const float4*)&a_src[lane * 4];
    float4 ad = *(const float4*)&a_dst[lane * 4];
    float ps = f01.x * as.x + f01.y * as.y + f23.x * as.z + f23.y * as.w;
    float pd = f01.x * ad.x + f01.y * ad.y + f23.x * ad.z + f23.y * ad.w;
    const int GS = 64 / HEADS;
    #pragma unroll
    for (int off = 1; off < GS; off <<= 1) {
        ps += __shfl_xor(ps, off);
        pd += __shfl_xor(pd, off);
    }
    int g = lane / GS;
    int r = lane & (GS - 1);
    if (r == 0) s_out[(size_t)node * HEADS + g] = ps;
    if (r == 1) d_out_[(size_t)node * HEADS + g] = pd;
}

// ---------------- fused one-pass online segment-softmax + aggregate + bias + ELU ------
template<int HEADS>
__global__ __launch_bounds__(256) void agg_kernel(const int* __restrict__ rowptr, const int* __restrict__ csr_src,
                                                  const __half* __restrict__ h, const float* __restrict__ s_att,
                                                  const float* __restrict__ d_att, const float* __restrict__ bias,
                                                  float* __restrict__ out, int nnodes) {
    int lane = threadIdx.x & 63;
    int node = blockIdx.x * 4 + (threadIdx.x >> 6);
    if (node >= nnodes) return;
    const int hh = (HEADS == 8) ? (lane >> 3) : 0;
    const int cbase = lane * 4;
    const int begin = rowptr[node], end = rowptr[node + 1];
    const float dl = d_att[(size_t)node * HEADS + hh];
    float m = -1e30f, den = 0.f;
    float ax = 0.f, ay = 0.f, az = 0.f, aw = 0.f;
    int i = begin;
    for (; i + 4 <= end; i += 4) {
        int s0 = csr_src[i], s1 = csr_src[i + 1], s2 = csr_src[i + 2], s3 = csr_src[i + 3];
        uint2 u0 = *(const uint2*)(h + (size_t)s0 * 256 + cbase);
        uint2 u1 = *(const uint2*)(h + (size_t)s1 * 256 + cbase);
        uint2 u2 = *(const uint2*)(h + (size_t)s2 * 256 + cbase);
        uint2 u3 = *(const uint2*)(h + (size_t)s3 * 256 + cbase);
        float v0 = lrelu(s_att[(size_t)s0 * HEADS + hh] + dl);
        float v1 = lrelu(s_att[(size_t)s1 * HEADS + hh] + dl);
        float v2 = lrelu(s_att[(size_t)s2 * HEADS + hh] + dl);
        float v3 = lrelu(s_att[(size_t)s3 * HEADS + hh] + dl);
        float vb = fmaxf(fmaxf(v0, v1), fmaxf(v2, v3));
        float mn = fmaxf(m, vb);
        float sc = __expf(m - mn);
        float w0 = __expf(v0 - mn), w1 = __expf(v1 - mn);
        float w2 = __expf(v2 - mn), w3 = __expf(v3 - mn);
        m = mn;
        den = den * sc + (w0 + w1) + (w2 + w3);
        float2 f0a = __half22float2(*(const __half2*)&u0.x), f0b = __half22float2(*(const __half2*)&u0.y);
        float2 f1a = __half22float2(*(const __half2*)&u1.x), f1b = __half22float2(*(const __half2*)&u1.y);
        float2 f2a = __half22float2(*(const __half2*)&u2.x), f2b = __half22float2(*(const __half2*)&u2.y);
        float2 f3a = __half22float2(*(const __half2*)&u3.x), f3b = __half22float2(*(const __half2*)&u3.y);
        ax = ax * sc + w0 * f0a.x + w1 * f1a.x + w2 * f2a.x + w3 * f3a.x;
        ay = ay * sc + w0 * f0a.y + w1 * f1a.y + w2 * f2a.y + w3 * f3a.y;
        az = az * sc + w0 * f0b.x + w1 * f1b.x + w2 * f2b.x + w3 * f3b.x;
        aw = aw * sc + w0 * f0b.y + w1 * f1b.y + w2 * f2b.y + w3 * f3b.y;
    }
    for (; i < end; ++i) {
        int s0 = csr_src[i];
        uint2 u0 = *(const uint2*)(h + (size_t)s0 * 256 + cbase);
        float v0 = lrelu(s_att[(size_t)s0 * HEADS + hh] + dl);
        float mn = fmaxf(m, v0);
        float sc = __expf(m - mn);
        float w0 = __expf(v0 - mn);
        m = mn;
        den = den * sc + w0;
        float2 f0a = __half22float2(*(const __half2*)&u0.x), f0b = __half22float2(*(const __half2*)&u0.y);
        ax = ax * sc + w0 * f0a.x;
        ay = ay * sc + w0 * f0a.y;
        az = az * sc + w0 * f0b.x;
        aw = aw * sc + w0 * f0b.y;
    }
    float inv = 1.0f / den;
    float4 bv = *(const float4*)&bias[cbase];
    float4 r;
    r.x = elu_f(ax * inv + bv.x);
    r.y = elu_f(ay * inv + bv.y);
    r.z = elu_f(az * inv + bv.z);
    r.w = elu_f(aw * inv + bv.w);
    *(float4*)&out[(size_t)node * 256 + cbase] = r;
}

extern "C" void kernel_launch(void* const* d_in, const int* in_sizes, int n_in,
                              void* d_out, int out_size, void* d_ws, size_t ws_size,
                              hipStream_t stream) {
    const float* x      = (const float*)d_in[0];
    const int*   ei     = (const int*)d_in[1];
    const float* W1     = (const float*)d_in[2];
    const float* a_src1 = (const float*)d_in[3];
    const float* a_dst1 = (const float*)d_in[4];
    const float* b1     = (const float*)d_in[5];
    const float* W2     = (const float*)d_in[6];
    const float* a_src2 = (const float*)d_in[7];
    const float* a_dst2 = (const float*)d_in[8];
    const float* b2     = (const float*)d_in[9];
    const float* Wlin   = (const float*)d_in[10];
    const float* blin   = (const float*)d_in[11];
    float* out = (float*)d_out;

    const int N = in_sizes[0] / 256;   // 50000 nodes
    const int E = in_sizes[1] / 2;     // 800000 edges
    const int ET = E + N;
    const int NB = (N + 255) / 256;

    char* p = (char*)d_ws;
    auto alloc = [&](size_t bytes) {
        void* r = (void*)p;
        p += (bytes + 255) & ~size_t(255);
        return r;
    };
    __half* bufH  = (__half*)alloc((size_t)N * 256 * 2);
    float* bufB   = (float*)alloc((size_t)N * 256 * 4);
    float* s1     = (float*)alloc((size_t)N * 8 * 4);
    float* d1     = (float*)alloc((size_t)N * 8 * 4);
    float* s2     = (float*)alloc((size_t)N * 4);
    float* d2     = (float*)alloc((size_t)N * 4);
    int*   deg    = (int*)alloc((size_t)N * 4);
    int*   cursor = (int*)alloc((size_t)N * 4);
    int*   rowptr = (int*)alloc((size_t)(N + 1) * 4);
    int*   csr    = (int*)alloc((size_t)ET * 4);
    int*   bsums  = (int*)alloc((size_t)NB * 4);
    int*   boff   = (int*)alloc((size_t)NB * 4);
    short* W1h    = (short*)alloc((size_t)256 * 256 * 2);
    short* W1l    = (short*)alloc((size_t)256 * 256 * 2);
    short* W2h    = (short*)alloc((size_t)256 * 256 * 2);
    short* W2l    = (short*)alloc((size_t)256 * 256 * 2);
    short* W3h    = (short*)alloc((size_t)256 * 64 * 2);
    short* W3l    = (short*)alloc((size_t)256 * 64 * 2);

    // ---- CSR build (parallel scan) ----
    hipMemsetAsync(deg, 0, (size_t)N * 4, stream);
    hist_kernel<<<(ET + 255) / 256, 256, 0, stream>>>(ei, deg, E, N);
    partial_kernel<<<NB, 256, 0, stream>>>(deg, bsums, N);
    scanblocks_kernel<<<1, 256, 0, stream>>>(bsums, boff, rowptr, NB, N);
    finalize_kernel<<<NB, 256, 0, stream>>>(deg, boff, rowptr, cursor, N);
    scatter_kernel<<<(ET + 255) / 256, 256, 0, stream>>>(ei, cursor, csr, E, N);

    // ---- weight pre-pack ----
    wconv_kernel<<<(256 * 256 + 255) / 256, 256, 0, stream>>>(W1, W1h, W1l, 256 * 256, 256);
    wconv_kernel<<<(256 * 256 + 255) / 256, 256, 0, stream>>>(W2, W2h, W2l, 256 * 256, 256);
    wconv_kernel<<<(256 * 64 + 255) / 256, 256, 0, stream>>>(Wlin, W3h, W3l, 256 * 64, 64);

    const int gBlocks = (N + 63) / 64;
    const int nodeBlocks = (N + 3) / 4;

    // ---- layer 1 ----
    gemm_mfma<256, true><<<gBlocks, 256, 0, stream>>>(x, W1h, W1l, nullptr, bufH, N);
    sd_kernel<8><<<nodeBlocks, 256, 0, stream>>>(bufH, a_src1, a_dst1, s1, d1, N);
    agg_kernel<8><<<nodeBlocks, 256, 0, stream>>>(rowptr, csr, bufH, s1, d1, b1, bufB, N);

    // ---- layer 2 ----
    gemm_mfma<256, true><<<gBlocks, 256, 0, stream>>>(bufB, W2h, W2l, nullptr, bufH, N);
    sd_kernel<1><<<nodeBlocks, 256, 0, stream>>>(bufH, a_src2, a_dst2, s2, d2, N);
    agg_kernel<1><<<nodeBlocks, 256, 0, stream>>>(rowptr, csr, bufH, s2, d2, b2, bufB, N);

    // ---- final linear ----
    gemm_mfma<64, false><<<gBlocks, 256, 0, stream>>>(bufB, W3h, W3l, blin, out, N);
}